// Round 9
// baseline (138.747 us; speedup 1.0000x reference)
//
#include <hip/hip_runtime.h>
#include <hip/hip_bf16.h>

typedef float f32x4 __attribute__((ext_vector_type(4)));
typedef short short8 __attribute__((ext_vector_type(8)));

static __device__ __forceinline__ short f2bf(float x) {
  union { __hip_bfloat16 b; short s; } u;
  u.b = __float2bfloat16(x);
  return u.s;
}

// build a bf16 A/B fragment from 8 consecutive f32 (in-register cvt)
static __device__ __forceinline__ short8 cvt8(const float* __restrict__ p) {
  const float4 lo = *(const float4*)p;
  const float4 hi = *(const float4*)(p + 4);
  short8 v;
  v[0] = f2bf(lo.x); v[1] = f2bf(lo.y); v[2] = f2bf(lo.z); v[3] = f2bf(lo.w);
  v[4] = f2bf(hi.x); v[5] = f2bf(hi.y); v[6] = f2bf(hi.z); v[7] = f2bf(hi.w);
  return v;
}

// ---------------------------------------------------------------------------
// MFMA projection GEMM, f32 sources converted in-register.
// Blocks 0..227: q-proj (nodes -> qb bf16). 228..739: kv-proj (kb bf16 + vT).
// ---------------------------------------------------------------------------
__global__ __launch_bounds__(256, 4)
void gemm_qkv_mfma(const float* __restrict__ nodes, const float* __restrict__ Wq,
                   const float* __restrict__ bq, short* __restrict__ qb,
                   const float* __restrict__ images, const float* __restrict__ Wkv,
                   const float* __restrict__ bkv, short* __restrict__ kb,
                   short* __restrict__ vT) {
  const int t = threadIdx.x, w = t >> 6, lane = t & 63;
  const int fr = lane & 15, fk = lane >> 4;
  int bid = blockIdx.x;
  const float *A, *W, *bias; int M, m0, n0, kvmode;
  if (bid < 228) {
    A = nodes; W = Wq; bias = bq; M = 3600; kvmode = 0;
    m0 = (bid >> 2) * 64; n0 = (bid & 3) * 64;
  } else {
    bid -= 228;
    A = images; W = Wkv; bias = bkv; M = 4096; kvmode = 1;
    m0 = (bid >> 3) * 64; n0 = (bid & 7) * 64;
  }
  int arow = m0 + w * 16 + fr; if (arow > M - 1) arow = M - 1;
  f32x4 acc[4];
  #pragma unroll
  for (int s = 0; s < 4; ++s) acc[s] = (f32x4){0.f, 0.f, 0.f, 0.f};
  #pragma unroll 2
  for (int k0 = 0; k0 < 256; k0 += 32) {
    const short8 af = cvt8(&A[(size_t)arow * 256 + k0 + fk * 8]);
    #pragma unroll
    for (int s = 0; s < 4; ++s) {
      const short8 wf = cvt8(&W[(size_t)(n0 + s * 16 + fr) * 256 + k0 + fk * 8]);
      acc[s] = __builtin_amdgcn_mfma_f32_16x16x32_bf16(af, wf, acc[s], 0, 0, 0);
    }
  }
  #pragma unroll
  for (int s = 0; s < 4; ++s)
    #pragma unroll
    for (int r = 0; r < 4; ++r) {
      const int m = m0 + w * 16 + fk * 4 + r;
      const int n = n0 + s * 16 + fr;
      const float val = acc[s][r] + bias[n];
      if (kvmode == 0) {
        if (m < 3600) qb[(size_t)m * 256 + n] = f2bf(val);
      } else {
        if (n < 256)
          kb[(size_t)m * 256 + n] = f2bf(val);
        else
          vT[((size_t)(m >> 10) * 256 + (n - 256)) * 1024 + (m & 1023)] =
              f2bf(val);
      }
    }
}

// out-proj: out[3600,256] = obuf_bf @ Wo^T + bo (Wo f32, cvt in-register)
__global__ __launch_bounds__(256, 4)
void gemm_out_mfma(const short* __restrict__ ob, const float* __restrict__ Wo,
                   const float* __restrict__ bo, float* __restrict__ out) {
  const int t = threadIdx.x, w = t >> 6, lane = t & 63;
  const int fr = lane & 15, fk = lane >> 4;
  const int m0 = (blockIdx.x >> 2) * 64, n0 = (blockIdx.x & 3) * 64;
  int arow = m0 + w * 16 + fr; if (arow > 3599) arow = 3599;
  f32x4 acc[4];
  #pragma unroll
  for (int s = 0; s < 4; ++s) acc[s] = (f32x4){0.f, 0.f, 0.f, 0.f};
  #pragma unroll 2
  for (int k0 = 0; k0 < 256; k0 += 32) {
    const short8 af = *(const short8*)&ob[(size_t)arow * 256 + k0 + fk * 8];
    #pragma unroll
    for (int s = 0; s < 4; ++s) {
      const short8 wf = cvt8(&Wo[(size_t)(n0 + s * 16 + fr) * 256 + k0 + fk * 8]);
      acc[s] = __builtin_amdgcn_mfma_f32_16x16x32_bf16(af, wf, acc[s], 0, 0, 0);
    }
  }
  #pragma unroll
  for (int s = 0; s < 4; ++s)
    #pragma unroll
    for (int r = 0; r < 4; ++r) {
      const int m = m0 + w * 16 + fk * 4 + r;
      const int n = n0 + s * 16 + fr;
      if (m < 3600) out[(size_t)m * 256 + n] = acc[s][r] + bo[n];
    }
}

// ---------------------------------------------------------------------------
// KV-split fused cpb-MLP + flash attention, software-pipelined:
//   iter c: QK(c) -> softmax(c) -> [issue K/V(c+1), dist(c+2) loads]
//           -> MLP(c+1) into cpb[(c+1)&1] -> lgkmcnt(0) -> PV(c) -> s_barrier
// MLP VALU hides the exp chain, the ps LDS round-trip, and K/V latency.
// One raw barrier per chunk (no vmcnt drain). Defer-max softmax (THR=8).
// ---------------------------------------------------------------------------
#define SCALE 0.17677669529663687f

#define BAR()                                              \
  asm volatile("s_waitcnt lgkmcnt(0)" ::: "memory");       \
  __builtin_amdgcn_s_barrier();                            \
  asm volatile("" ::: "memory")

// cpb MLP for 4 tiles (64 pairs of this wave's 2 q-rows x 32 keys)
#define MLP_TILES(D2, CPB)                                                    \
  _Pragma("unroll")                                                           \
  for (int t4 = 0; t4 < 4; ++t4) {                                            \
    const float dx = (D2)[t4].x, dy = (D2)[t4].y;                             \
    short8 a0, a1;                                                            \
    _Pragma("unroll")                                                         \
    for (int jj = 0; jj < 8; ++jj) {                                          \
      const float h0 =                                                        \
          fmaxf(fmaf(w1x[0][jj], dx, fmaf(w1y[0][jj], dy, w1b[0][jj])), 0.f); \
      const float h1 =                                                        \
          fmaxf(fmaf(w1x[1][jj], dx, fmaf(w1y[1][jj], dy, w1b[1][jj])), 0.f); \
      a0[jj] = f2bf(h0);                                                      \
      a1[jj] = f2bf(h1);                                                      \
    }                                                                         \
    f32x4 zm = {0.f, 0.f, 0.f, 0.f};                                          \
    f32x4 dcp = __builtin_amdgcn_mfma_f32_16x16x32_bf16(a1, w2f[1], zm, 0, 0, 0); \
    dcp = __builtin_amdgcn_mfma_f32_16x16x32_bf16(a0, w2f[0], dcp, 0, 0, 0);  \
    const int qloc = 2 * w + (t4 >> 1);                                       \
    const int kbase = (t4 & 1) * 16;                                          \
    if (fr < 8) {                                                             \
      _Pragma("unroll")                                                       \
      for (int rr = 0; rr < 4; ++rr)                                          \
        (CPB)[fr * 552 + qloc * 34 + kbase + fk * 4 + rr] = dcp[rr] + b2add;  \
    }                                                                         \
    __builtin_amdgcn_sched_barrier(0);                                        \
  }

template <int KLEN>
__global__ __launch_bounds__(512, 2)
void attn_part(const __hip_bfloat16* __restrict__ qb,   // [4*900,256]
               const __hip_bfloat16* __restrict__ kb,   // [4*1024,256]
               const __hip_bfloat16* __restrict__ vT,   // [4,256,1024]
               const float* __restrict__ dist,          // [4,900,1024,2]
               const unsigned char* __restrict__ mask,  // [4,1024]
               const float* __restrict__ Wc1, const float* __restrict__ bc1,
               const float* __restrict__ Wc2, const float* __restrict__ bc2,
               float* __restrict__ Opart,               // [NS,4*912,256]
               float* __restrict__ msplit,              // [NS,4,8,912]
               float* __restrict__ lsplit) {
  constexpr int NCH = KLEN / 32;
  __shared__ float cpb_s[2][8 * 552];  // double-buffered [h][q*34+k]
  __shared__ short ps_s[8][640];       // per-wave P bf16 [q][40 pad]

  const int t    = threadIdx.x;
  const int b    = blockIdx.x / 57;
  const int q0   = (blockIdx.x % 57) * 16;
  const int sp   = blockIdx.y;
  const int kb0  = sp * KLEN;
  const int w    = t >> 6;
  const int lane = t & 63;
  const int fr   = lane & 15;
  const int fk   = lane >> 4;

  // --- per-lane MLP layer-1 weights ---
  float w1x[2][8], w1y[2][8], w1b[2][8];
  #pragma unroll
  for (int m = 0; m < 2; ++m)
    #pragma unroll
    for (int jj = 0; jj < 8; ++jj) {
      const int j = m * 32 + fk * 8 + jj;
      w1x[m][jj] = Wc1[2 * j];
      w1y[m][jj] = Wc1[2 * j + 1];
      w1b[m][jj] = bc1[j];
    }
  // --- W2 register B-frag ---
  short8 w2f[2];
  #pragma unroll
  for (int m = 0; m < 2; ++m)
    #pragma unroll
    for (int jj = 0; jj < 8; ++jj) {
      const float v = (fr < 8) ? Wc2[fr * 64 + m * 32 + fk * 8 + jj] : 0.f;
      w2f[m][jj] = f2bf(v);
    }
  const float b2add = (fr < 8) ? bc2[fr] : 0.f;

  // --- Q A-frag (persistent) ---
  int qrow = q0 + fr; if (qrow > 899) qrow = 899;
  const short8 aq = *(const short8*)&qb[(size_t)(b * 900 + qrow) * 256 +
                                        w * 32 + fk * 8];

  // --- dist pointers ---
  const float* dptr[4];
  #pragma unroll
  for (int t4 = 0; t4 < 4; ++t4) {
    int qg = q0 + 2 * w + (t4 >> 1); if (qg > 899) qg = 899;
    dptr[t4] = dist +
        ((size_t)(b * 900 + qg) * 1024 + kb0 + (t4 & 1) * 16 + fr) * 2;
  }

  f32x4 of[2];
  of[0] = (f32x4){0.f, 0.f, 0.f, 0.f};
  of[1] = (f32x4){0.f, 0.f, 0.f, 0.f};
  float mreg[4], lreg[4];
  #pragma unroll
  for (int r = 0; r < 4; ++r) { mreg[r] = -1e30f; lreg[r] = 0.f; }

  // ---- prologue: MLP(0) -> cpb[0]; stage dist(1); issue K/V(0) ----
  float2 d2now[4];
  {
    float2 d2c0[4];
    #pragma unroll
    for (int t4 = 0; t4 < 4; ++t4) d2c0[t4] = *(const float2*)dptr[t4];
    MLP_TILES(d2c0, cpb_s[0])
    const int c1 = (NCH > 1) ? 1 : 0;
    #pragma unroll
    for (int t4 = 0; t4 < 4; ++t4)
      d2now[t4] = *(const float2*)(dptr[t4] + (size_t)c1 * 64);
  }
  short8 kf0 = *(const short8*)
      &kb[(size_t)(b * 1024 + kb0 + fr) * 256 + w * 32 + fk * 8];
  short8 kf1 = *(const short8*)
      &kb[(size_t)(b * 1024 + kb0 + 16 + fr) * 256 + w * 32 + fk * 8];
  short8 bv0 = *(const short8*)
      &vT[(size_t)(b * 256 + w * 32 + fr) * 1024 + kb0 + fk * 8];
  short8 bv1 = *(const short8*)
      &vT[(size_t)(b * 256 + w * 32 + 16 + fr) * 1024 + kb0 + fk * 8];
  bool mk0 = mask[b * 1024 + kb0 + fr] != 0;
  bool mk1 = mask[b * 1024 + kb0 + 16 + fr] != 0;

  BAR();   // cpb[0] visible; vm prefetches stay in flight

  for (int c = 0; c < NCH; ++c) {
    const float* cpb_c = cpb_s[c & 1];
    float* cpb_n = cpb_s[(c + 1) & 1];

    // ---- QK(c): 2 MFMA ----
    f32x4 z = {0.f, 0.f, 0.f, 0.f};
    __builtin_amdgcn_s_setprio(1);
    const f32x4 sc0 = __builtin_amdgcn_mfma_f32_16x16x32_bf16(aq, kf0, z, 0, 0, 0);
    const f32x4 sc1 = __builtin_amdgcn_mfma_f32_16x16x32_bf16(aq, kf1, z, 0, 0, 0);
    __builtin_amdgcn_s_setprio(0);

    // ---- defer-max online softmax (THR=8) ----
    float s0v[4], s1v[4];
    bool need = false;
    #pragma unroll
    for (int r = 0; r < 4; ++r) {
      const int q = fk * 4 + r;
      const float cv0 = cpb_c[w * 552 + q * 34 + fr];
      const float cv1 = cpb_c[w * 552 + q * 34 + 16 + fr];
      s0v[r] = mk0 ? -1e30f : fmaf(sc0[r], SCALE, cv0);
      s1v[r] = mk1 ? -1e30f : fmaf(sc1[r], SCALE, cv1);
      need = need || (fmaxf(s0v[r], s1v[r]) > mreg[r] + 8.f);
    }
    if (__any((int)need)) {        // slow path (chunk 0 + rare growth)
      #pragma unroll
      for (int r = 0; r < 4; ++r) {
        float mx = fmaxf(s0v[r], s1v[r]);
        mx = fmaxf(mx, __shfl_xor(mx, 1));
        mx = fmaxf(mx, __shfl_xor(mx, 2));
        mx = fmaxf(mx, __shfl_xor(mx, 4));
        mx = fmaxf(mx, __shfl_xor(mx, 8));
        const float mnew = fmaxf(mreg[r], mx);
        const float al = __expf(mreg[r] - mnew);
        of[0][r] *= al;
        of[1][r] *= al;
        lreg[r] *= al;
        mreg[r] = mnew;
      }
    }
    #pragma unroll
    for (int r = 0; r < 4; ++r) {
      const int q = fk * 4 + r;
      const float p0 = __expf(s0v[r] - mreg[r]);
      const float p1 = __expf(s1v[r] - mreg[r]);
      ps_s[w][q * 40 + fr]      = f2bf(p0);
      ps_s[w][q * 40 + 16 + fr] = f2bf(p1);
      lreg[r] += p0 + p1;         // per-lane partial (own 2 columns)
    }

    // ---- issue next-chunk K/V/mask + dist(c+2) loads (hide under MLP) ----
    short8 kf0n = kf0, kf1n = kf1, bv0n = bv0, bv1n = bv1;
    bool mk0n = mk0, mk1n = mk1;
    if (c + 1 < NCH) {
      const int k1 = kb0 + (c + 1) * 32;
      kf0n = *(const short8*)
          &kb[(size_t)(b * 1024 + k1 + fr) * 256 + w * 32 + fk * 8];
      kf1n = *(const short8*)
          &kb[(size_t)(b * 1024 + k1 + 16 + fr) * 256 + w * 32 + fk * 8];
      bv0n = *(const short8*)
          &vT[(size_t)(b * 256 + w * 32 + fr) * 1024 + k1 + fk * 8];
      bv1n = *(const short8*)
          &vT[(size_t)(b * 256 + w * 32 + 16 + fr) * 1024 + k1 + fk * 8];
      mk0n = mask[b * 1024 + k1 + fr] != 0;
      mk1n = mask[b * 1024 + k1 + 16 + fr] != 0;
    }
    float2 d2nx[4];
    {
      const int cn2 = (c + 2 < NCH) ? c + 2 : NCH - 1;
      #pragma unroll
      for (int t4 = 0; t4 < 4; ++t4)
        d2nx[t4] = *(const float2*)(dptr[t4] + (size_t)cn2 * 64);
    }

    // ---- MLP(c+1) -> cpb_n (overlaps exp chain + load latency) ----
    if (c + 1 < NCH) {
      MLP_TILES(d2now, cpb_n)
    }

    // ---- drain LDS (ps + cpb writes), then PV(c) ----
    asm volatile("s_waitcnt lgkmcnt(0)" ::: "memory");
    __builtin_amdgcn_sched_barrier(0);
    const short8 ap = *(const short8*)&ps_s[w][fr * 40 + fk * 8];
    __builtin_amdgcn_s_setprio(1);
    of[0] = __builtin_amdgcn_mfma_f32_16x16x32_bf16(ap, bv0, of[0], 0, 0, 0);
    of[1] = __builtin_amdgcn_mfma_f32_16x16x32_bf16(ap, bv1, of[1], 0, 0, 0);
    __builtin_amdgcn_s_setprio(0);

    // ---- rotate prefetched state ----
    kf0 = kf0n; kf1 = kf1n; bv0 = bv0n; bv1 = bv1n;
    mk0 = mk0n; mk1 = mk1n;
    #pragma unroll
    for (int t4 = 0; t4 < 4; ++t4) d2now[t4] = d2nx[t4];

    BAR();   // cpb_n visible for next iter; raw barrier (no vmcnt drain)
  }

  // ---- reduce per-lane l partials across the row's 16 lanes ----
  #pragma unroll
  for (int r = 0; r < 4; ++r) {
    lreg[r] += __shfl_xor(lreg[r], 1);
    lreg[r] += __shfl_xor(lreg[r], 2);
    lreg[r] += __shfl_xor(lreg[r], 4);
    lreg[r] += __shfl_xor(lreg[r], 8);
  }

  // ---- emit partials (unnormalized O, m, l) ----
  #pragma unroll
  for (int s = 0; s < 2; ++s)
    #pragma unroll
    for (int r = 0; r < 4; ++r) {
      const int qg = q0 + fk * 4 + r;
      Opart[((size_t)sp * 3648 + b * 912 + qg) * 256 + w * 32 + s * 16 + fr] =
          of[s][r];
    }
  if (fr == 0) {
    #pragma unroll
    for (int r = 0; r < 4; ++r) {
      const int qg = q0 + fk * 4 + r;
      msplit[((sp * 4 + b) * 8 + w) * 912 + qg] = mreg[r];
      lsplit[((sp * 4 + b) * 8 + w) * 912 + qg] = lreg[r];
    }
  }
}

// ---------------------------------------------------------------------------
// Merge NS partials -> bf16 obuf
// ---------------------------------------------------------------------------
template <int NS>
__global__ __launch_bounds__(256)
void attn_combine(const float* __restrict__ Opart,
                  const float* __restrict__ msplit,
                  const float* __restrict__ lsplit,
                  short* __restrict__ obuf) {
  const int row = blockIdx.x;            // b*900+q
  const int b = row / 900, q = row - b * 900;
  const int e = threadIdx.x, h = e >> 5;
  float mv[NS], M = -1e30f;
  #pragma unroll
  for (int s = 0; s < NS; ++s) {
    mv[s] = msplit[((s * 4 + b) * 8 + h) * 912 + q];
    M = fmaxf(M, mv[s]);
  }
  float L = 0.f, val = 0.f;
  #pragma unroll
  for (int s = 0; s < NS; ++s) {
    const float wgt = __expf(mv[s] - M);
    L = fmaf(lsplit[((s * 4 + b) * 8 + h) * 912 + q], wgt, L);
    val = fmaf(Opart[((size_t)s * 3648 + b * 912 + q) * 256 + e], wgt, val);
  }
  obuf[(size_t)row * 256 + e] = f2bf(val / L);
}

// ---------------------------------------------------------------------------
extern "C" void kernel_launch(void* const* d_in, const int* in_sizes, int n_in,
                              void* d_out, int out_size, void* d_ws, size_t ws_size,
                              hipStream_t stream) {
  const float* nodes  = (const float*)d_in[0];
  const float* images = (const float*)d_in[1];
  const unsigned char* mask = (const unsigned char*)d_in[2];
  const float* dist   = (const float*)d_in[3];
  const float* Wq     = (const float*)d_in[4];
  const float* bq     = (const float*)d_in[5];
  const float* Wkv    = (const float*)d_in[6];
  const float* bkv    = (const float*)d_in[7];
  const float* Wc1    = (const float*)d_in[8];
  const float* bc1    = (const float*)d_in[9];
  const float* Wc2    = (const float*)d_in[10];
  const float* bc2    = (const float*)d_in[11];
  const float* Wo     = (const float*)d_in[12];
  const float* bo     = (const float*)d_in[13];
  float* out = (float*)d_out;

  // ---- workspace ----
  char* wp = (char*)d_ws;
  short* qb = (short*)wp;                       // 1,843,200 (reused as obuf_bf)
  short* kb = (short*)(wp + 1843200);           // 2,097,152
  short* vT = (short*)(wp + 3940352);           // 2,097,152
  char*  S  = wp + 6037504;
  float* Opart = (float*)S;

  const size_t need4 = 6037504u + 4u * 3735552u + 4u * 2u * 116736u;
  const size_t need2 = 6037504u + 2u * 3735552u + 2u * 2u * 116736u;
  int nsplit = 1;
  if (ws_size >= need4) nsplit = 4;
  else if (ws_size >= need2) nsplit = 2;
  float* msplit = Opart + (size_t)nsplit * 3648 * 256;
  float* lsplit = msplit + (size_t)nsplit * 4 * 8 * 912;
  short* obuf_bf = qb;                          // qb dead after attn

  gemm_qkv_mfma<<<740, 256, 0, stream>>>(nodes, Wq, bq, qb,
                                         images, Wkv, bkv, kb, vT);

  if (nsplit == 4) {
    attn_part<256><<<dim3(228, 4), 512, 0, stream>>>(
        (const __hip_bfloat16*)qb, (const __hip_bfloat16*)kb,
        (const __hip_bfloat16*)vT, dist, mask, Wc1, bc1, Wc2, bc2,
        Opart, msplit, lsplit);
    attn_combine<4><<<3600, 256, 0, stream>>>(Opart, msplit, lsplit, obuf_bf);
  } else if (nsplit == 2) {
    attn_part<512><<<dim3(228, 2), 512, 0, stream>>>(
        (const __hip_bfloat16*)qb, (const __hip_bfloat16*)kb,
        (const __hip_bfloat16*)vT, dist, mask, Wc1, bc1, Wc2, bc2,
        Opart, msplit, lsplit);
    attn_combine<2><<<3600, 256, 0, stream>>>(Opart, msplit, lsplit, obuf_bf);
  } else {
    attn_part<1024><<<dim3(228, 1), 512, 0, stream>>>(
        (const __hip_bfloat16*)qb, (const __hip_bfloat16*)kb,
        (const __hip_bfloat16*)vT, dist, mask, Wc1, bc1, Wc2, bc2,
        Opart, msplit, lsplit);
    attn_combine<1><<<3600, 256, 0, stream>>>(Opart, msplit, lsplit, obuf_bf);
  }

  gemm_out_mfma<<<228, 256, 0, stream>>>(obuf_bf, Wo, bo, out);
}

// Round 11
// 131.306 us; speedup vs baseline: 1.0567x; 1.0567x over previous
//
#include <hip/hip_runtime.h>
#include <hip/hip_bf16.h>

typedef float f32x4 __attribute__((ext_vector_type(4)));
typedef short short8 __attribute__((ext_vector_type(8)));

static __device__ __forceinline__ short f2bf(float x) {
  union { __hip_bfloat16 b; short s; } u;
  u.b = __float2bfloat16(x);
  return u.s;
}

// build a bf16 A/B fragment from 8 consecutive f32 (in-register cvt, RNE)
static __device__ __forceinline__ short8 cvt8(const float* __restrict__ p) {
  const float4 lo = *(const float4*)p;
  const float4 hi = *(const float4*)(p + 4);
  short8 v;
  v[0] = f2bf(lo.x); v[1] = f2bf(lo.y); v[2] = f2bf(lo.z); v[3] = f2bf(lo.w);
  v[4] = f2bf(hi.x); v[5] = f2bf(hi.y); v[6] = f2bf(hi.z); v[7] = f2bf(hi.w);
  return v;
}

// ---------------------------------------------------------------------------
// MFMA projection GEMM, f32 sources converted in-register (R8-exact).
// Blocks 0..227: q-proj (nodes -> qb bf16). 228..739: kv-proj (kb bf16 + vT).
// ---------------------------------------------------------------------------
__global__ __launch_bounds__(256, 4)
void gemm_qkv_mfma(const float* __restrict__ nodes, const float* __restrict__ Wq,
                   const float* __restrict__ bq, short* __restrict__ qb,
                   const float* __restrict__ images, const float* __restrict__ Wkv,
                   const float* __restrict__ bkv, short* __restrict__ kb,
                   short* __restrict__ vT) {
  const int t = threadIdx.x, w = t >> 6, lane = t & 63;
  const int fr = lane & 15, fk = lane >> 4;
  int bid = blockIdx.x;
  const float *A, *W, *bias; int M, m0, n0, kvmode;
  if (bid < 228) {
    A = nodes; W = Wq; bias = bq; M = 3600; kvmode = 0;
    m0 = (bid >> 2) * 64; n0 = (bid & 3) * 64;
  } else {
    bid -= 228;
    A = images; W = Wkv; bias = bkv; M = 4096; kvmode = 1;
    m0 = (bid >> 3) * 64; n0 = (bid & 7) * 64;
  }
  int arow = m0 + w * 16 + fr; if (arow > M - 1) arow = M - 1;
  f32x4 acc[4];
  #pragma unroll
  for (int s = 0; s < 4; ++s) acc[s] = (f32x4){0.f, 0.f, 0.f, 0.f};
  #pragma unroll 2
  for (int k0 = 0; k0 < 256; k0 += 32) {
    const short8 af = cvt8(&A[(size_t)arow * 256 + k0 + fk * 8]);
    #pragma unroll
    for (int s = 0; s < 4; ++s) {
      const short8 wf = cvt8(&W[(size_t)(n0 + s * 16 + fr) * 256 + k0 + fk * 8]);
      acc[s] = __builtin_amdgcn_mfma_f32_16x16x32_bf16(af, wf, acc[s], 0, 0, 0);
    }
  }
  #pragma unroll
  for (int s = 0; s < 4; ++s)
    #pragma unroll
    for (int r = 0; r < 4; ++r) {
      const int m = m0 + w * 16 + fk * 4 + r;
      const int n = n0 + s * 16 + fr;
      const float val = acc[s][r] + bias[n];
      if (kvmode == 0) {
        if (m < 3600) qb[(size_t)m * 256 + n] = f2bf(val);
      } else {
        if (n < 256)
          kb[(size_t)m * 256 + n] = f2bf(val);
        else
          vT[((size_t)(m >> 10) * 256 + (n - 256)) * 1024 + (m & 1023)] =
              f2bf(val);
      }
    }
}

// ---------------------------------------------------------------------------
// Fused combine + out-proj: A-frag built from Opart/msplit/lsplit in-register
// (flash-decoding merge, normalize, scalar f2bf pack), then MFMA against Wo.
// ---------------------------------------------------------------------------
template <int NS>
__global__ __launch_bounds__(256, 4)
void gemm_out_combine(const float* __restrict__ Opart,   // [NS,4*912,256]
                      const float* __restrict__ msplit,  // [NS,4,8,912]
                      const float* __restrict__ lsplit,
                      const float* __restrict__ Wo, const float* __restrict__ bo,
                      float* __restrict__ out) {
  const int t = threadIdx.x, w = t >> 6, lane = t & 63;
  const int fr = lane & 15, fk = lane >> 4;
  const int m0 = (blockIdx.x >> 2) * 64, n0 = (blockIdx.x & 3) * 64;
  int arow = m0 + w * 16 + fr; if (arow > 3599) arow = 3599;
  const int b = arow / 900, q = arow - b * 900;
  const int row912 = b * 912 + q;
  f32x4 acc[4];
  #pragma unroll
  for (int s = 0; s < 4; ++s) acc[s] = (f32x4){0.f, 0.f, 0.f, 0.f};
  #pragma unroll 2
  for (int k0 = 0; k0 < 256; k0 += 32) {
    const int h = k0 >> 5;              // all 8 lane dims lie in this head
    float mv[NS], M = -1e30f;
    #pragma unroll
    for (int s = 0; s < NS; ++s) {
      mv[s] = msplit[((s * 4 + b) * 8 + h) * 912 + q];
      M = fmaxf(M, mv[s]);
    }
    float L = 0.f, wgt[NS];
    #pragma unroll
    for (int s = 0; s < NS; ++s) {
      wgt[s] = __expf(mv[s] - M);
      L = fmaf(lsplit[((s * 4 + b) * 8 + h) * 912 + q], wgt[s], L);
    }
    const float rL = 1.f / L;
    float av[8];
    #pragma unroll
    for (int j = 0; j < 8; ++j) av[j] = 0.f;
    #pragma unroll
    for (int s = 0; s < NS; ++s) {
      const float* op = &Opart[((size_t)s * 3648 + row912) * 256 + k0 + fk * 8];
      const float4 o0 = *(const float4*)op;
      const float4 o1 = *(const float4*)(op + 4);
      const float ws = wgt[s] * rL;
      av[0] = fmaf(o0.x, ws, av[0]); av[1] = fmaf(o0.y, ws, av[1]);
      av[2] = fmaf(o0.z, ws, av[2]); av[3] = fmaf(o0.w, ws, av[3]);
      av[4] = fmaf(o1.x, ws, av[4]); av[5] = fmaf(o1.y, ws, av[5]);
      av[6] = fmaf(o1.z, ws, av[6]); av[7] = fmaf(o1.w, ws, av[7]);
    }
    short8 af;
    #pragma unroll
    for (int j = 0; j < 8; ++j) af[j] = f2bf(av[j]);
    #pragma unroll
    for (int s = 0; s < 4; ++s) {
      const short8 wf = cvt8(&Wo[(size_t)(n0 + s * 16 + fr) * 256 + k0 + fk * 8]);
      acc[s] = __builtin_amdgcn_mfma_f32_16x16x32_bf16(af, wf, acc[s], 0, 0, 0);
    }
  }
  #pragma unroll
  for (int s = 0; s < 4; ++s)
    #pragma unroll
    for (int r = 0; r < 4; ++r) {
      const int m = m0 + w * 16 + fk * 4 + r;
      const int n = n0 + s * 16 + fr;
      if (m < 3600) out[(size_t)m * 256 + n] = acc[s][r] + bo[n];
    }
}

// ---------------------------------------------------------------------------
// KV-split fused cpb-MLP + flash attention (R8-exact kernel).
// ---------------------------------------------------------------------------
#define SCALE 0.17677669529663687f

#define BAR()                                              \
  asm volatile("s_waitcnt lgkmcnt(0)" ::: "memory");       \
  __builtin_amdgcn_s_barrier();                            \
  asm volatile("" ::: "memory")

template <int KLEN>
__global__ __launch_bounds__(512, 2)
void attn_part(const __hip_bfloat16* __restrict__ qb,   // [4*900,256]
               const __hip_bfloat16* __restrict__ kb,   // [4*1024,256]
               const __hip_bfloat16* __restrict__ vT,   // [4,256,1024]
               const float* __restrict__ dist,          // [4,900,1024,2]
               const unsigned char* __restrict__ mask,  // [4,1024]
               const float* __restrict__ Wc1, const float* __restrict__ bc1,
               const float* __restrict__ Wc2, const float* __restrict__ bc2,
               float* __restrict__ Opart,               // [NS,4*912,256]
               float* __restrict__ msplit,              // [NS,4,8,912]
               float* __restrict__ lsplit) {
  constexpr int NCH = KLEN / 32;
  __shared__ float cpb_s[2][8 * 552];  // double-buffered [h][q*34+k]
  __shared__ short ps_s[8][640];       // per-wave P bf16 [q][40 pad]

  const int t    = threadIdx.x;
  const int b    = blockIdx.x / 57;
  const int q0   = (blockIdx.x % 57) * 16;
  const int sp   = blockIdx.y;
  const int kb0  = sp * KLEN;
  const int w    = t >> 6;
  const int lane = t & 63;
  const int fr   = lane & 15;
  const int fk   = lane >> 4;

  // --- per-lane MLP layer-1 weights ---
  float w1x[2][8], w1y[2][8], w1b[2][8];
  #pragma unroll
  for (int m = 0; m < 2; ++m)
    #pragma unroll
    for (int jj = 0; jj < 8; ++jj) {
      const int j = m * 32 + fk * 8 + jj;
      w1x[m][jj] = Wc1[2 * j];
      w1y[m][jj] = Wc1[2 * j + 1];
      w1b[m][jj] = bc1[j];
    }
  // --- W2 register B-frag ---
  short8 w2f[2];
  #pragma unroll
  for (int m = 0; m < 2; ++m)
    #pragma unroll
    for (int jj = 0; jj < 8; ++jj) {
      const float v = (fr < 8) ? Wc2[fr * 64 + m * 32 + fk * 8 + jj] : 0.f;
      w2f[m][jj] = f2bf(v);
    }
  const float b2add = (fr < 8) ? bc2[fr] : 0.f;

  // --- Q A-frag (persistent) ---
  int qrow = q0 + fr; if (qrow > 899) qrow = 899;
  const short8 aq = *(const short8*)&qb[(size_t)(b * 900 + qrow) * 256 +
                                        w * 32 + fk * 8];

  // --- dist pointers + chunk-0 prefetch ---
  const float* dptr[4];
  float2 d2cur[4];
  #pragma unroll
  for (int t4 = 0; t4 < 4; ++t4) {
    int qg = q0 + 2 * w + (t4 >> 1); if (qg > 899) qg = 899;
    dptr[t4] = dist +
        ((size_t)(b * 900 + qg) * 1024 + kb0 + (t4 & 1) * 16 + fr) * 2;
    d2cur[t4] = *(const float2*)dptr[t4];
  }

  f32x4 of[2];
  of[0] = (f32x4){0.f, 0.f, 0.f, 0.f};
  of[1] = (f32x4){0.f, 0.f, 0.f, 0.f};
  float mreg[4], lreg[4];
  #pragma unroll
  for (int r = 0; r < 4; ++r) { mreg[r] = -1e30f; lreg[r] = 0.f; }

  for (int c = 0; c < NCH; ++c) {
    const int k0 = kb0 + c * 32;
    const int cn = (c < NCH - 1) ? c + 1 : c;
    float* cpb_c = cpb_s[c & 1];

    // ---- prefetch next dist; issue this chunk's K/V/mask ----
    float2 d2n[4];
    #pragma unroll
    for (int t4 = 0; t4 < 4; ++t4)
      d2n[t4] = *(const float2*)(dptr[t4] + (size_t)cn * 64);
    const short8 kf0 = *(const short8*)
        &kb[(size_t)(b * 1024 + k0 + fr) * 256 + w * 32 + fk * 8];
    const short8 kf1 = *(const short8*)
        &kb[(size_t)(b * 1024 + k0 + 16 + fr) * 256 + w * 32 + fk * 8];
    const short8 bv0 = *(const short8*)
        &vT[(size_t)(b * 256 + w * 32 + fr) * 1024 + k0 + fk * 8];
    const short8 bv1 = *(const short8*)
        &vT[(size_t)(b * 256 + w * 32 + 16 + fr) * 1024 + k0 + fk * 8];
    const bool mk0 = mask[b * 1024 + k0 + fr] != 0;
    const bool mk1 = mask[b * 1024 + k0 + 16 + fr] != 0;

    // ---- cpb MLP: 4 tiles x (layer1 VALU + 2 MFMA layer2) ----
    #pragma unroll
    for (int t4 = 0; t4 < 4; ++t4) {
      const float dx = d2cur[t4].x, dy = d2cur[t4].y;
      short8 a0, a1;
      #pragma unroll
      for (int jj = 0; jj < 8; ++jj) {
        const float h0 =
            fmaxf(fmaf(w1x[0][jj], dx, fmaf(w1y[0][jj], dy, w1b[0][jj])), 0.f);
        const float h1 =
            fmaxf(fmaf(w1x[1][jj], dx, fmaf(w1y[1][jj], dy, w1b[1][jj])), 0.f);
        a0[jj] = f2bf(h0);
        a1[jj] = f2bf(h1);
      }
      f32x4 z = {0.f, 0.f, 0.f, 0.f};
      f32x4 dcp = __builtin_amdgcn_mfma_f32_16x16x32_bf16(a1, w2f[1], z, 0, 0, 0);
      dcp = __builtin_amdgcn_mfma_f32_16x16x32_bf16(a0, w2f[0], dcp, 0, 0, 0);
      const int qloc = 2 * w + (t4 >> 1);
      const int kbase = (t4 & 1) * 16;
      if (fr < 8) {
        #pragma unroll
        for (int rr = 0; rr < 4; ++rr)
          cpb_c[fr * 552 + qloc * 34 + kbase + fk * 4 + rr] = dcp[rr] + b2add;
      }
      __builtin_amdgcn_sched_barrier(0);
    }

    // ---- single raw barrier: cpb visible, vm prefetches stay in flight ----
    BAR();

    // ---- QK: 2 MFMA ----
    f32x4 z = {0.f, 0.f, 0.f, 0.f};
    __builtin_amdgcn_s_setprio(1);
    const f32x4 sc0 = __builtin_amdgcn_mfma_f32_16x16x32_bf16(aq, kf0, z, 0, 0, 0);
    const f32x4 sc1 = __builtin_amdgcn_mfma_f32_16x16x32_bf16(aq, kf1, z, 0, 0, 0);
    __builtin_amdgcn_s_setprio(0);

    // ---- defer-max online softmax (THR=8) ----
    float s0v[4], s1v[4];
    bool need = false;
    #pragma unroll
    for (int r = 0; r < 4; ++r) {
      const int q = fk * 4 + r;
      const float cv0 = cpb_c[w * 552 + q * 34 + fr];
      const float cv1 = cpb_c[w * 552 + q * 34 + 16 + fr];
      s0v[r] = mk0 ? -1e30f : fmaf(sc0[r], SCALE, cv0);
      s1v[r] = mk1 ? -1e30f : fmaf(sc1[r], SCALE, cv1);
      need = need || (fmaxf(s0v[r], s1v[r]) > mreg[r] + 8.f);
    }
    if (__any((int)need)) {        // slow path (chunk 0 + rare growth)
      #pragma unroll
      for (int r = 0; r < 4; ++r) {
        float mx = fmaxf(s0v[r], s1v[r]);
        mx = fmaxf(mx, __shfl_xor(mx, 1));
        mx = fmaxf(mx, __shfl_xor(mx, 2));
        mx = fmaxf(mx, __shfl_xor(mx, 4));
        mx = fmaxf(mx, __shfl_xor(mx, 8));
        const float mnew = fmaxf(mreg[r], mx);
        const float al = __expf(mreg[r] - mnew);
        of[0][r] *= al;
        of[1][r] *= al;
        lreg[r] *= al;
        mreg[r] = mnew;
      }
    }
    #pragma unroll
    for (int r = 0; r < 4; ++r) {
      const int q = fk * 4 + r;
      const float p0 = __expf(s0v[r] - mreg[r]);
      const float p1 = __expf(s1v[r] - mreg[r]);
      ps_s[w][q * 40 + fr]      = f2bf(p0);
      ps_s[w][q * 40 + 16 + fr] = f2bf(p1);
      lreg[r] += p0 + p1;         // per-lane partial (own 2 columns)
    }

    // same-wave LDS write -> read: drain lgkm, pin order
    asm volatile("s_waitcnt lgkmcnt(0)" ::: "memory");
    __builtin_amdgcn_sched_barrier(0);

    // ---- PV: P A-frag + V B-frags, 2 MFMA ----
    const short8 ap = *(const short8*)&ps_s[w][fr * 40 + fk * 8];
    __builtin_amdgcn_s_setprio(1);
    of[0] = __builtin_amdgcn_mfma_f32_16x16x32_bf16(ap, bv0, of[0], 0, 0, 0);
    of[1] = __builtin_amdgcn_mfma_f32_16x16x32_bf16(ap, bv1, of[1], 0, 0, 0);
    __builtin_amdgcn_s_setprio(0);

    #pragma unroll
    for (int t4 = 0; t4 < 4; ++t4) d2cur[t4] = d2n[t4];
  }

  // ---- reduce per-lane l partials across the row's 16 lanes ----
  #pragma unroll
  for (int r = 0; r < 4; ++r) {
    lreg[r] += __shfl_xor(lreg[r], 1);
    lreg[r] += __shfl_xor(lreg[r], 2);
    lreg[r] += __shfl_xor(lreg[r], 4);
    lreg[r] += __shfl_xor(lreg[r], 8);
  }

  // ---- emit partials (unnormalized O, m, l) ----
  #pragma unroll
  for (int s = 0; s < 2; ++s)
    #pragma unroll
    for (int r = 0; r < 4; ++r) {
      const int qg = q0 + fk * 4 + r;
      Opart[((size_t)sp * 3648 + b * 912 + qg) * 256 + w * 32 + s * 16 + fr] =
          of[s][r];
    }
  if (fr == 0) {
    #pragma unroll
    for (int r = 0; r < 4; ++r) {
      const int qg = q0 + fk * 4 + r;
      msplit[((sp * 4 + b) * 8 + w) * 912 + qg] = mreg[r];
      lsplit[((sp * 4 + b) * 8 + w) * 912 + qg] = lreg[r];
    }
  }
}

// ---------------------------------------------------------------------------
extern "C" void kernel_launch(void* const* d_in, const int* in_sizes, int n_in,
                              void* d_out, int out_size, void* d_ws, size_t ws_size,
                              hipStream_t stream) {
  const float* nodes  = (const float*)d_in[0];
  const float* images = (const float*)d_in[1];
  const unsigned char* mask = (const unsigned char*)d_in[2];
  const float* dist   = (const float*)d_in[3];
  const float* Wq     = (const float*)d_in[4];
  const float* bq     = (const float*)d_in[5];
  const float* Wkv    = (const float*)d_in[6];
  const float* bkv    = (const float*)d_in[7];
  const float* Wc1    = (const float*)d_in[8];
  const float* bc1    = (const float*)d_in[9];
  const float* Wc2    = (const float*)d_in[10];
  const float* bc2    = (const float*)d_in[11];
  const float* Wo     = (const float*)d_in[12];
  const float* bo     = (const float*)d_in[13];
  float* out = (float*)d_out;

  // ---- workspace ----
  char* wp = (char*)d_ws;
  short* qb = (short*)wp;                       // 1,843,200
  short* kb = (short*)(wp + 1843200);           // 2,097,152
  short* vT = (short*)(wp + 3940352);           // 2,097,152
  char*  S  = wp + 6037504;
  float* Opart = (float*)S;

  const size_t need2 = 6037504u + 2u * 3735552u + 2u * 2u * 116736u;
  int nsplit = (ws_size >= need2) ? 2 : 1;
  float* msplit = Opart + (size_t)nsplit * 3648 * 256;
  float* lsplit = msplit + (size_t)nsplit * 4 * 8 * 912;

  gemm_qkv_mfma<<<740, 256, 0, stream>>>(nodes, Wq, bq, qb,
                                         images, Wkv, bkv, kb, vT);

  if (nsplit == 2) {
    attn_part<512><<<dim3(228, 2), 512, 0, stream>>>(
        (const __hip_bfloat16*)qb, (const __hip_bfloat16*)kb,
        (const __hip_bfloat16*)vT, dist, mask, Wc1, bc1, Wc2, bc2,
        Opart, msplit, lsplit);
    gemm_out_combine<2><<<228, 256, 0, stream>>>(Opart, msplit, lsplit,
                                                 Wo, bo, out);
  } else {
    attn_part<1024><<<dim3(228, 1), 512, 0, stream>>>(
        (const __hip_bfloat16*)qb, (const __hip_bfloat16*)kb,
        (const __hip_bfloat16*)vT, dist, mask, Wc1, bc1, Wc2, bc2,
        Opart, msplit, lsplit);
    gemm_out_combine<1><<<228, 256, 0, stream>>>(Opart, msplit, lsplit,
                                                 Wo, bo, out);
  }
}

// Round 13
// 117.457 us; speedup vs baseline: 1.1813x; 1.1179x over previous
//
#include <hip/hip_runtime.h>
#include <hip/hip_bf16.h>

typedef float f32x4 __attribute__((ext_vector_type(4)));
typedef short short8 __attribute__((ext_vector_type(8)));

static __device__ __forceinline__ short f2bf(float x) {
  union { __hip_bfloat16 b; short s; } u;
  u.b = __float2bfloat16(x);
  return u.s;
}

// ---------------------------------------------------------------------------
// f32 -> bf16 pre-cast: nodes | images | Wq | Wkv | Wo  (8 elems/thread)
// (R7-proven kernel; scalar RNE casts.)
// ---------------------------------------------------------------------------
__global__ __launch_bounds__(256)
void cvt_bf16(const float* __restrict__ nodes, const float* __restrict__ images,
              const float* __restrict__ Wq, const float* __restrict__ Wkv,
              const float* __restrict__ Wo,
              short* __restrict__ nb, short* __restrict__ ib,
              short* __restrict__ wqb, short* __restrict__ wkvb,
              short* __restrict__ wob) {
  const int idx = blockIdx.x * 256 + threadIdx.x;   // 0..279039
  const float* src; short* dst; int o;
  if      (idx < 115200) { src = nodes;  dst = nb;   o = idx; }
  else if (idx < 246272) { src = images; dst = ib;   o = idx - 115200; }
  else if (idx < 254464) { src = Wq;     dst = wqb;  o = idx - 246272; }
  else if (idx < 270848) { src = Wkv;    dst = wkvb; o = idx - 254464; }
  else                   { src = Wo;     dst = wob;  o = idx - 270848; }
  const float4 a = ((const float4*)src)[o * 2];
  const float4 b = ((const float4*)src)[o * 2 + 1];
  short8 v;
  v[0] = f2bf(a.x); v[1] = f2bf(a.y); v[2] = f2bf(a.z); v[3] = f2bf(a.w);
  v[4] = f2bf(b.x); v[5] = f2bf(b.y); v[6] = f2bf(b.z); v[7] = f2bf(b.w);
  *(short8*)&dst[o * 8] = v;
}

// ---------------------------------------------------------------------------
// MFMA projection GEMMs on pre-cast bf16 (R7-proven).
// Blocks 0..227: q-proj (nb -> qb). 228..739: kv-proj (kb bf16 + vT).
// ---------------------------------------------------------------------------
__global__ __launch_bounds__(256, 4)
void gemm_qkv_mfma(const short* __restrict__ nb, const short* __restrict__ wqb,
                   const float* __restrict__ bq, short* __restrict__ qb,
                   const short* __restrict__ ib, const short* __restrict__ wkvb,
                   const float* __restrict__ bkv, short* __restrict__ kb,
                   short* __restrict__ vT) {
  const int t = threadIdx.x, w = t >> 6, lane = t & 63;
  const int fr = lane & 15, fk = lane >> 4;
  int bid = blockIdx.x;
  const short *A, *W; const float* bias; int M, m0, n0, kvmode;
  if (bid < 228) {
    A = nb; W = wqb; bias = bq; M = 3600; kvmode = 0;
    m0 = (bid >> 2) * 64; n0 = (bid & 3) * 64;
  } else {
    bid -= 228;
    A = ib; W = wkvb; bias = bkv; M = 4096; kvmode = 1;
    m0 = (bid >> 3) * 64; n0 = (bid & 7) * 64;
  }
  int arow = m0 + w * 16 + fr; if (arow > M - 1) arow = M - 1;
  f32x4 acc[4];
  #pragma unroll
  for (int s = 0; s < 4; ++s) acc[s] = (f32x4){0.f, 0.f, 0.f, 0.f};
  #pragma unroll 2
  for (int k0 = 0; k0 < 256; k0 += 32) {
    const short8 af = *(const short8*)&A[(size_t)arow * 256 + k0 + fk * 8];
    #pragma unroll
    for (int s = 0; s < 4; ++s) {
      const short8 wf =
          *(const short8*)&W[(size_t)(n0 + s * 16 + fr) * 256 + k0 + fk * 8];
      acc[s] = __builtin_amdgcn_mfma_f32_16x16x32_bf16(af, wf, acc[s], 0, 0, 0);
    }
  }
  #pragma unroll
  for (int s = 0; s < 4; ++s)
    #pragma unroll
    for (int r = 0; r < 4; ++r) {
      const int m = m0 + w * 16 + fk * 4 + r;
      const int n = n0 + s * 16 + fr;
      const float val = acc[s][r] + bias[n];
      if (kvmode == 0) {
        if (m < 3600) qb[(size_t)m * 256 + n] = f2bf(val);
      } else {
        if (n < 256)
          kb[(size_t)m * 256 + n] = f2bf(val);
        else
          vT[((size_t)(m >> 10) * 256 + (n - 256)) * 1024 + (m & 1023)] =
              f2bf(val);
      }
    }
}

// ---------------------------------------------------------------------------
// Fused combine + out-proj: merge NS split partials in-register (scalar f2bf
// pack, R11-proven), Wo pre-cast to bf16 (no in-loop weight cvt).
// ---------------------------------------------------------------------------
template <int NS>
__global__ __launch_bounds__(256, 4)
void gemm_out_combine(const float* __restrict__ Opart,   // [NS,4*912,256]
                      const float* __restrict__ msplit,  // [NS,4,8,912]
                      const float* __restrict__ lsplit,
                      const short* __restrict__ wob, const float* __restrict__ bo,
                      float* __restrict__ out) {
  const int t = threadIdx.x, w = t >> 6, lane = t & 63;
  const int fr = lane & 15, fk = lane >> 4;
  const int m0 = (blockIdx.x >> 2) * 64, n0 = (blockIdx.x & 3) * 64;
  int arow = m0 + w * 16 + fr; if (arow > 3599) arow = 3599;
  const int b = arow / 900, q = arow - b * 900;
  const int row912 = b * 912 + q;
  f32x4 acc[4];
  #pragma unroll
  for (int s = 0; s < 4; ++s) acc[s] = (f32x4){0.f, 0.f, 0.f, 0.f};
  #pragma unroll 2
  for (int k0 = 0; k0 < 256; k0 += 32) {
    const int h = k0 >> 5;              // all 8 lane dims lie in this head
    float mv[NS], M = -1e30f;
    #pragma unroll
    for (int s = 0; s < NS; ++s) {
      mv[s] = msplit[((s * 4 + b) * 8 + h) * 912 + q];
      M = fmaxf(M, mv[s]);
    }
    float L = 0.f, wgt[NS];
    #pragma unroll
    for (int s = 0; s < NS; ++s) {
      wgt[s] = __expf(mv[s] - M);
      L = fmaf(lsplit[((s * 4 + b) * 8 + h) * 912 + q], wgt[s], L);
    }
    const float rL = 1.f / L;
    float av[8];
    #pragma unroll
    for (int j = 0; j < 8; ++j) av[j] = 0.f;
    #pragma unroll
    for (int s = 0; s < NS; ++s) {
      const float* op = &Opart[((size_t)s * 3648 + row912) * 256 + k0 + fk * 8];
      const float4 o0 = *(const float4*)op;
      const float4 o1 = *(const float4*)(op + 4);
      const float ws = wgt[s] * rL;
      av[0] = fmaf(o0.x, ws, av[0]); av[1] = fmaf(o0.y, ws, av[1]);
      av[2] = fmaf(o0.z, ws, av[2]); av[3] = fmaf(o0.w, ws, av[3]);
      av[4] = fmaf(o1.x, ws, av[4]); av[5] = fmaf(o1.y, ws, av[5]);
      av[6] = fmaf(o1.z, ws, av[6]); av[7] = fmaf(o1.w, ws, av[7]);
    }
    short8 af;
    #pragma unroll
    for (int j = 0; j < 8; ++j) af[j] = f2bf(av[j]);
    #pragma unroll
    for (int s = 0; s < 4; ++s) {
      const short8 wf =
          *(const short8*)&wob[(size_t)(n0 + s * 16 + fr) * 256 + k0 + fk * 8];
      acc[s] = __builtin_amdgcn_mfma_f32_16x16x32_bf16(af, wf, acc[s], 0, 0, 0);
    }
  }
  #pragma unroll
  for (int s = 0; s < 4; ++s)
    #pragma unroll
    for (int r = 0; r < 4; ++r) {
      const int m = m0 + w * 16 + fk * 4 + r;
      const int n = n0 + s * 16 + fr;
      if (m < 3600) out[(size_t)m * 256 + n] = acc[s][r] + bo[n];
    }
}

// ---------------------------------------------------------------------------
// KV-split fused cpb-MLP + flash attention (byte-exact R11 passing kernel).
// ---------------------------------------------------------------------------
#define SCALE 0.17677669529663687f

#define BAR()                                              \
  asm volatile("s_waitcnt lgkmcnt(0)" ::: "memory");       \
  __builtin_amdgcn_s_barrier();                            \
  asm volatile("" ::: "memory")

template <int KLEN>
__global__ __launch_bounds__(512, 2)
void attn_part(const __hip_bfloat16* __restrict__ qb,   // [4*900,256]
               const __hip_bfloat16* __restrict__ kb,   // [4*1024,256]
               const __hip_bfloat16* __restrict__ vT,   // [4,256,1024]
               const float* __restrict__ dist,          // [4,900,1024,2]
               const unsigned char* __restrict__ mask,  // [4,1024]
               const float* __restrict__ Wc1, const float* __restrict__ bc1,
               const float* __restrict__ Wc2, const float* __restrict__ bc2,
               float* __restrict__ Opart,               // [NS,4*912,256]
               float* __restrict__ msplit,              // [NS,4,8,912]
               float* __restrict__ lsplit) {
  constexpr int NCH = KLEN / 32;
  __shared__ float cpb_s[2][8 * 552];  // double-buffered [h][q*34+k]
  __shared__ short ps_s[8][640];       // per-wave P bf16 [q][40 pad]

  const int t    = threadIdx.x;
  const int b    = blockIdx.x / 57;
  const int q0   = (blockIdx.x % 57) * 16;
  const int sp   = blockIdx.y;
  const int kb0  = sp * KLEN;
  const int w    = t >> 6;
  const int lane = t & 63;
  const int fr   = lane & 15;
  const int fk   = lane >> 4;

  // --- per-lane MLP layer-1 weights ---
  float w1x[2][8], w1y[2][8], w1b[2][8];
  #pragma unroll
  for (int m = 0; m < 2; ++m)
    #pragma unroll
    for (int jj = 0; jj < 8; ++jj) {
      const int j = m * 32 + fk * 8 + jj;
      w1x[m][jj] = Wc1[2 * j];
      w1y[m][jj] = Wc1[2 * j + 1];
      w1b[m][jj] = bc1[j];
    }
  // --- W2 register B-frag ---
  short8 w2f[2];
  #pragma unroll
  for (int m = 0; m < 2; ++m)
    #pragma unroll
    for (int jj = 0; jj < 8; ++jj) {
      const float v = (fr < 8) ? Wc2[fr * 64 + m * 32 + fk * 8 + jj] : 0.f;
      w2f[m][jj] = f2bf(v);
    }
  const float b2add = (fr < 8) ? bc2[fr] : 0.f;

  // --- Q A-frag (persistent) ---
  int qrow = q0 + fr; if (qrow > 899) qrow = 899;
  const short8 aq = *(const short8*)&qb[(size_t)(b * 900 + qrow) * 256 +
                                        w * 32 + fk * 8];

  // --- dist pointers + chunk-0 prefetch ---
  const float* dptr[4];
  float2 d2cur[4];
  #pragma unroll
  for (int t4 = 0; t4 < 4; ++t4) {
    int qg = q0 + 2 * w + (t4 >> 1); if (qg > 899) qg = 899;
    dptr[t4] = dist +
        ((size_t)(b * 900 + qg) * 1024 + kb0 + (t4 & 1) * 16 + fr) * 2;
    d2cur[t4] = *(const float2*)dptr[t4];
  }

  f32x4 of[2];
  of[0] = (f32x4){0.f, 0.f, 0.f, 0.f};
  of[1] = (f32x4){0.f, 0.f, 0.f, 0.f};
  float mreg[4], lreg[4];
  #pragma unroll
  for (int r = 0; r < 4; ++r) { mreg[r] = -1e30f; lreg[r] = 0.f; }

  for (int c = 0; c < NCH; ++c) {
    const int k0 = kb0 + c * 32;
    const int cn = (c < NCH - 1) ? c + 1 : c;
    float* cpb_c = cpb_s[c & 1];

    // ---- prefetch next dist; issue this chunk's K/V/mask ----
    float2 d2n[4];
    #pragma unroll
    for (int t4 = 0; t4 < 4; ++t4)
      d2n[t4] = *(const float2*)(dptr[t4] + (size_t)cn * 64);
    const short8 kf0 = *(const short8*)
        &kb[(size_t)(b * 1024 + k0 + fr) * 256 + w * 32 + fk * 8];
    const short8 kf1 = *(const short8*)
        &kb[(size_t)(b * 1024 + k0 + 16 + fr) * 256 + w * 32 + fk * 8];
    const short8 bv0 = *(const short8*)
        &vT[(size_t)(b * 256 + w * 32 + fr) * 1024 + k0 + fk * 8];
    const short8 bv1 = *(const short8*)
        &vT[(size_t)(b * 256 + w * 32 + 16 + fr) * 1024 + k0 + fk * 8];
    const bool mk0 = mask[b * 1024 + k0 + fr] != 0;
    const bool mk1 = mask[b * 1024 + k0 + 16 + fr] != 0;

    // ---- cpb MLP: 4 tiles x (layer1 VALU + 2 MFMA layer2) ----
    #pragma unroll
    for (int t4 = 0; t4 < 4; ++t4) {
      const float dx = d2cur[t4].x, dy = d2cur[t4].y;
      short8 a0, a1;
      #pragma unroll
      for (int jj = 0; jj < 8; ++jj) {
        const float h0 =
            fmaxf(fmaf(w1x[0][jj], dx, fmaf(w1y[0][jj], dy, w1b[0][jj])), 0.f);
        const float h1 =
            fmaxf(fmaf(w1x[1][jj], dx, fmaf(w1y[1][jj], dy, w1b[1][jj])), 0.f);
        a0[jj] = f2bf(h0);
        a1[jj] = f2bf(h1);
      }
      f32x4 z = {0.f, 0.f, 0.f, 0.f};
      f32x4 dcp = __builtin_amdgcn_mfma_f32_16x16x32_bf16(a1, w2f[1], z, 0, 0, 0);
      dcp = __builtin_amdgcn_mfma_f32_16x16x32_bf16(a0, w2f[0], dcp, 0, 0, 0);
      const int qloc = 2 * w + (t4 >> 1);
      const int kbase = (t4 & 1) * 16;
      if (fr < 8) {
        #pragma unroll
        for (int rr = 0; rr < 4; ++rr)
          cpb_c[fr * 552 + qloc * 34 + kbase + fk * 4 + rr] = dcp[rr] + b2add;
      }
      __builtin_amdgcn_sched_barrier(0);
    }

    // ---- single raw barrier: cpb visible, vm prefetches stay in flight ----
    BAR();

    // ---- QK: 2 MFMA ----
    f32x4 z = {0.f, 0.f, 0.f, 0.f};
    __builtin_amdgcn_s_setprio(1);
    const f32x4 sc0 = __builtin_amdgcn_mfma_f32_16x16x32_bf16(aq, kf0, z, 0, 0, 0);
    const f32x4 sc1 = __builtin_amdgcn_mfma_f32_16x16x32_bf16(aq, kf1, z, 0, 0, 0);
    __builtin_amdgcn_s_setprio(0);

    // ---- defer-max online softmax (THR=8) ----
    float s0v[4], s1v[4];
    bool need = false;
    #pragma unroll
    for (int r = 0; r < 4; ++r) {
      const int q = fk * 4 + r;
      const float cv0 = cpb_c[w * 552 + q * 34 + fr];
      const float cv1 = cpb_c[w * 552 + q * 34 + 16 + fr];
      s0v[r] = mk0 ? -1e30f : fmaf(sc0[r], SCALE, cv0);
      s1v[r] = mk1 ? -1e30f : fmaf(sc1[r], SCALE, cv1);
      need = need || (fmaxf(s0v[r], s1v[r]) > mreg[r] + 8.f);
    }
    if (__any((int)need)) {        // slow path (chunk 0 + rare growth)
      #pragma unroll
      for (int r = 0; r < 4; ++r) {
        float mx = fmaxf(s0v[r], s1v[r]);
        mx = fmaxf(mx, __shfl_xor(mx, 1));
        mx = fmaxf(mx, __shfl_xor(mx, 2));
        mx = fmaxf(mx, __shfl_xor(mx, 4));
        mx = fmaxf(mx, __shfl_xor(mx, 8));
        const float mnew = fmaxf(mreg[r], mx);
        const float al = __expf(mreg[r] - mnew);
        of[0][r] *= al;
        of[1][r] *= al;
        lreg[r] *= al;
        mreg[r] = mnew;
      }
    }
    #pragma unroll
    for (int r = 0; r < 4; ++r) {
      const int q = fk * 4 + r;
      const float p0 = __expf(s0v[r] - mreg[r]);
      const float p1 = __expf(s1v[r] - mreg[r]);
      ps_s[w][q * 40 + fr]      = f2bf(p0);
      ps_s[w][q * 40 + 16 + fr] = f2bf(p1);
      lreg[r] += p0 + p1;         // per-lane partial (own 2 columns)
    }

    // same-wave LDS write -> read: drain lgkm, pin order
    asm volatile("s_waitcnt lgkmcnt(0)" ::: "memory");
    __builtin_amdgcn_sched_barrier(0);

    // ---- PV: P A-frag + V B-frags, 2 MFMA ----
    const short8 ap = *(const short8*)&ps_s[w][fr * 40 + fk * 8];
    __builtin_amdgcn_s_setprio(1);
    of[0] = __builtin_amdgcn_mfma_f32_16x16x32_bf16(ap, bv0, of[0], 0, 0, 0);
    of[1] = __builtin_amdgcn_mfma_f32_16x16x32_bf16(ap, bv1, of[1], 0, 0, 0);
    __builtin_amdgcn_s_setprio(0);

    #pragma unroll
    for (int t4 = 0; t4 < 4; ++t4) d2cur[t4] = d2n[t4];
  }

  // ---- reduce per-lane l partials across the row's 16 lanes ----
  #pragma unroll
  for (int r = 0; r < 4; ++r) {
    lreg[r] += __shfl_xor(lreg[r], 1);
    lreg[r] += __shfl_xor(lreg[r], 2);
    lreg[r] += __shfl_xor(lreg[r], 4);
    lreg[r] += __shfl_xor(lreg[r], 8);
  }

  // ---- emit partials (unnormalized O, m, l) ----
  #pragma unroll
  for (int s = 0; s < 2; ++s)
    #pragma unroll
    for (int r = 0; r < 4; ++r) {
      const int qg = q0 + fk * 4 + r;
      Opart[((size_t)sp * 3648 + b * 912 + qg) * 256 + w * 32 + s * 16 + fr] =
          of[s][r];
    }
  if (fr == 0) {
    #pragma unroll
    for (int r = 0; r < 4; ++r) {
      const int qg = q0 + fk * 4 + r;
      msplit[((sp * 4 + b) * 8 + w) * 912 + qg] = mreg[r];
      lsplit[((sp * 4 + b) * 8 + w) * 912 + qg] = lreg[r];
    }
  }
}

// ---------------------------------------------------------------------------
extern "C" void kernel_launch(void* const* d_in, const int* in_sizes, int n_in,
                              void* d_out, int out_size, void* d_ws, size_t ws_size,
                              hipStream_t stream) {
  const float* nodes  = (const float*)d_in[0];
  const float* images = (const float*)d_in[1];
  const unsigned char* mask = (const unsigned char*)d_in[2];
  const float* dist   = (const float*)d_in[3];
  const float* Wq     = (const float*)d_in[4];
  const float* bq     = (const float*)d_in[5];
  const float* Wkv    = (const float*)d_in[6];
  const float* bkv    = (const float*)d_in[7];
  const float* Wc1    = (const float*)d_in[8];
  const float* bc1    = (const float*)d_in[9];
  const float* Wc2    = (const float*)d_in[10];
  const float* bc2    = (const float*)d_in[11];
  const float* Wo     = (const float*)d_in[12];
  const float* bo     = (const float*)d_in[13];
  float* out = (float*)d_out;

  // ---- workspace layout with phase overlays (R7-proven scheme) ----
  char* wp = (char*)d_ws;
  short* qb = (short*)wp;                       // 1,843,200
  short* kb = (short*)(wp + 1843200);           // 2,097,152
  short* vT = (short*)(wp + 3940352);           // 2,097,152
  char*  S  = wp + 6037504;
  // phase 1 (cvt outputs, dead after gemm_qkv):
  short* nb   = (short*)S;                      // 1,843,200
  short* ib   = (short*)(S + 1843200);          // 2,097,152
  short* wqb  = (short*)(S + 3940352);          //   131,072
  short* wkvb = (short*)(S + 4071424);          //   262,144 (ends 4,333,568)
  // phase 2 (attn partials) overlays S:
  float* Opart = (float*)S;

  const size_t need2 = 6037504u + 7938048u + 131072u;   // 14,106,624
  int nsplit = (ws_size >= need2) ? 2 : 1;
  const size_t Ssize = (nsplit == 2)
      ? 7938048u                                 // 2*(3,735,552) + 2*2*116,736
      : 4333568u;                                // max(phase1, 1-split phase2)
  short* wob = (short*)(S + Ssize);             // 131,072 (persists to last)
  float* msplit = Opart + (size_t)nsplit * 3648 * 256;
  float* lsplit = msplit + (size_t)nsplit * 4 * 8 * 912;

  cvt_bf16<<<1090, 256, 0, stream>>>(nodes, images, Wq, Wkv, Wo,
                                     nb, ib, wqb, wkvb, wob);
  gemm_qkv_mfma<<<740, 256, 0, stream>>>(nb, wqb, bq, qb, ib, wkvb, bkv, kb, vT);

  if (nsplit == 2) {
    attn_part<512><<<dim3(228, 2), 512, 0, stream>>>(
        (const __hip_bfloat16*)qb, (const __hip_bfloat16*)kb,
        (const __hip_bfloat16*)vT, dist, mask, Wc1, bc1, Wc2, bc2,
        Opart, msplit, lsplit);
    gemm_out_combine<2><<<228, 256, 0, stream>>>(Opart, msplit, lsplit,
                                                 wob, bo, out);
  } else {
    attn_part<1024><<<dim3(228, 1), 512, 0, stream>>>(
        (const __hip_bfloat16*)qb, (const __hip_bfloat16*)kb,
        (const __hip_bfloat16*)vT, dist, mask, Wc1, bc1, Wc2, bc2,
        Opart, msplit, lsplit);
    gemm_out_combine<1><<<228, 256, 0, stream>>>(Opart, msplit, lsplit,
                                                 wob, bo, out);
  }
}